// Round 4
// baseline (188.726 us; speedup 1.0000x reference)
//
#include <hip/hip_runtime.h>

typedef __attribute__((ext_vector_type(8))) short bf16x8;
typedef __attribute__((ext_vector_type(4))) float f32x4;
typedef __attribute__((ext_vector_type(16))) float f32x16;

__device__ __forceinline__ unsigned short f2bf(float f) {
  union { float f; unsigned u; } a; a.f = f;
  unsigned u = a.u;
  u += 0x7fffu + ((u >> 16) & 1u);   // round-to-nearest-even
  return (unsigned short)(u >> 16);
}
__device__ __forceinline__ unsigned pk(float a, float b) {
  return (unsigned)f2bf(a) | ((unsigned)f2bf(b) << 16);
}

// ---------------------------------------------------------------------------
// Prep: build Bt[tap][n][k] bf16 in workspace.
//   n = opc*4 + q_out  (q minor -> acc regs = quaternion comps)
//   k = c*4   + q_in   (q minor -> one float4 pixel-channel = 8B of k)
// ---------------------------------------------------------------------------
__global__ void prep_bt(const float* __restrict__ wr, const float* __restrict__ wi,
                        const float* __restrict__ wj, const float* __restrict__ wk,
                        unsigned short* __restrict__ btg) {
  int idx = blockIdx.x * 256 + threadIdx.x;          // 9*256*256 = 589824
  if (idx >= 9 * 256 * 256) return;
  int tap = idx >> 16;
  int rem = idx & 65535;
  int n = rem >> 8, k = rem & 255;
  int opc = n >> 2, qo = n & 3, c = k >> 2, qi = k & 3;
  const int   comp[4][4] = {{0,1,2,3},{1,0,3,2},{2,3,0,1},{3,2,1,0}};
  const float sgn [4][4] = {{1.f,-1.f,-1.f,-1.f},{1.f,1.f,-1.f,1.f},
                            {1.f,1.f,1.f,-1.f},{1.f,-1.f,1.f,1.f}};
  int ci = comp[qo][qi];
  const float* wp = (ci == 0) ? wr : (ci == 1) ? wi : (ci == 2) ? wj : wk;
  float v = sgn[qo][qi] * wp[(opc * 64 + c) * 9 + tap];
  btg[idx] = f2bf(v);
}

// ---------------------------------------------------------------------------
// Main: implicit-GEMM quaternion conv, 32x32x16 MFMA.
// Block: 256 threads = 4 waves; tile = 128 px (2 image rows) x 128 N.
// Wave (wm, wnh): 64 px (tile-row wm) x 64 N (half wnh). acc[2][2] = 64 AGPR.
// Grid 1024 = 3 blocks/CU resident (launch_bounds(256,3), LDS 33.8KB).
// LDS layout k-slot-major: xwin[hh 0..3][kslot 0..7][col 0..65] x 16B.
//   -> A-frag read = 512B contiguous, stage write = 1024B contiguous:
//      both bank-conflict-free by construction (no swizzle).
// Weights read per-fragment from L2 (btg = 1.18 MB, resident).
// ---------------------------------------------------------------------------
__launch_bounds__(256, 3)
__global__ void qconv_main(const float* __restrict__ x,
                           const unsigned short* __restrict__ btg,
                           const float* __restrict__ bias,
                           float* __restrict__ out) {
  __shared__ char xwin[4 * 8 * 66 * 16];   // 33792 B

  const int tid = threadIdx.x;
  // XCD-aware swizzle: 1024 blocks, 8 XCDs -> 128 consecutive per XCD
  const int nb  = (blockIdx.x & 7) * 128 + (blockIdx.x >> 3);
  const int mt  = nb >> 1;              // pixel tile 0..511
  const int nt  = nb & 1;               // N half
  const int b   = mt >> 5;              // image
  const int h0  = (mt & 31) * 2;        // first of 2 image rows

  const int lane = tid & 63;
  const int wid  = tid >> 6;
  const int wm   = wid & 1;             // tile row owned by this wave
  const int wnh  = wid >> 1;            // 0..1: 64-wide N half of 128
  const int l31  = lane & 31;
  const int l32  = lane >> 5;

  const int w_ = lane;                  // staging column 0..63
  const int sh = wid;                   // staging window row 0..3

  // zero-fill padding cols 0 and 65 for all (hh, kslot): 64 x 16B
  if (tid < 64) {
    int hh = tid >> 4, ks = (tid >> 1) & 7, col = (tid & 1) ? 65 : 0;
    *reinterpret_cast<f32x4*>(xwin + ((hh * 8 + ks) * 66 + col) * 16) =
        (f32x4){0.f, 0.f, 0.f, 0.f};
  }

  f32x16 acc[2][2];
#pragma unroll
  for (int i = 0; i < 2; ++i)
#pragma unroll
    for (int j = 0; j < 2; ++j)
      acc[i][j] = (f32x16)(0.f);

  for (int ch = 0; ch < 4; ++ch) {
    __syncthreads();   // previous chunk fully consumed (and pad fill on ch 0)

    // ---- stage: 16 c x 4 rows x 64 cols; 2 channels -> one 16B kslot ----
    const int hp = h0 + sh - 1;
    const bool inb = (hp >= 0) && (hp < 64);
#pragma unroll
    for (int i = 0; i < 8; ++i) {        // i == kslot == channel pair
      int c0 = ch * 16 + i * 2;
      float4 v0 = make_float4(0.f, 0.f, 0.f, 0.f), v1 = v0;
      if (inb) {
        const float* p =
            x + (size_t)((((b * 64 + c0) * 64 + hp) * 64 + w_) * 4);
        v0 = *reinterpret_cast<const float4*>(p);
        v1 = *reinterpret_cast<const float4*>(p + 16384);  // next channel
      }
      uint4 u = make_uint4(pk(v0.x, v0.y), pk(v0.z, v0.w),
                           pk(v1.x, v1.y), pk(v1.z, v1.w));
      *reinterpret_cast<uint4*>(
          xwin + ((sh * 8 + i) * 66 + (w_ + 1)) * 16) = u;
    }
    __syncthreads();   // xwin ready

    // weight element index base (units of u16): [tap][n][k]
    const unsigned short* wb =
        btg + (size_t)(nt * 128 + wnh * 64 + l31) * 256 + ch * 64 + l32 * 8;

#pragma unroll
    for (int tap = 0; tap < 9; ++tap) {
      const int dh = tap / 3 - 1;
      const int dw = tap % 3 - 1;
      const int hh = wm + dh + 1;                 // 0..3
#pragma unroll
      for (int kst = 0; kst < 4; ++kst) {
        bf16x8 wf[2], pf[2];
#pragma unroll
        for (int fn = 0; fn < 2; ++fn)
          wf[fn] = *reinterpret_cast<const bf16x8*>(
              wb + tap * 65536 + fn * 8192 + kst * 16);
#pragma unroll
        for (int fm = 0; fm < 2; ++fm) {
          int wc = fm * 32 + l31 + dw + 1;        // 0..65
          pf[fm] = *reinterpret_cast<const bf16x8*>(
              xwin + ((hh * 8 + kst * 2 + l32) * 66 + wc) * 16);
        }
        __builtin_amdgcn_s_setprio(1);
#pragma unroll
        for (int fn = 0; fn < 2; ++fn)
#pragma unroll
          for (int fm = 0; fm < 2; ++fm)
            acc[fn][fm] = __builtin_amdgcn_mfma_f32_32x32x16_bf16(
                wf[fn], pf[fm], acc[fn][fm], 0, 0, 0);
        __builtin_amdgcn_s_setprio(0);
      }
    }
  }

  // ---- epilogue: D row=(reg&3)+8*(reg>>2)+4*l32 -> reg&3 == q component ----
  const int h = h0 + wm;
#pragma unroll
  for (int fn = 0; fn < 2; ++fn) {
#pragma unroll
    for (int fm = 0; fm < 2; ++fm) {
      int w = fm * 32 + l31;
#pragma unroll
      for (int g = 0; g < 4; ++g) {
        int opc = nt * 32 + wnh * 16 + fn * 8 + g * 2 + l32;
        f32x4 v = {acc[fn][fm][4 * g + 0], acc[fn][fm][4 * g + 1],
                   acc[fn][fm][4 * g + 2], acc[fn][fm][4 * g + 3]};
        v.x += bias[opc];   // bias only on real component
        *reinterpret_cast<f32x4*>(
            out + (size_t)((((b * 64 + opc) * 64 + h) * 64 + w) * 4)) = v;
      }
    }
  }
}

extern "C" void kernel_launch(void* const* d_in, const int* in_sizes, int n_in,
                              void* d_out, int out_size, void* d_ws, size_t ws_size,
                              hipStream_t stream) {
  const float* x    = (const float*)d_in[0];
  const float* wr   = (const float*)d_in[1];
  const float* wi   = (const float*)d_in[2];
  const float* wj   = (const float*)d_in[3];
  const float* wk   = (const float*)d_in[4];
  const float* bias = (const float*)d_in[5];
  unsigned short* btg = (unsigned short*)d_ws;   // 9*256*256*2 = 1.18 MB

  prep_bt<<<2304, 256, 0, stream>>>(wr, wi, wj, wk, btg);
  qconv_main<<<1024, 256, 0, stream>>>(x, btg, bias, (float*)d_out);
}

// Round 5
// 152.092 us; speedup vs baseline: 1.2409x; 1.2409x over previous
//
#include <hip/hip_runtime.h>

typedef __attribute__((ext_vector_type(8))) short bf16x8;
typedef __attribute__((ext_vector_type(4))) float f32x4;
typedef __attribute__((ext_vector_type(16))) float f32x16;

__device__ __forceinline__ unsigned short f2bf(float f) {
  union { float f; unsigned u; } a; a.f = f;
  unsigned u = a.u;
  u += 0x7fffu + ((u >> 16) & 1u);   // round-to-nearest-even
  return (unsigned short)(u >> 16);
}
__device__ __forceinline__ unsigned pk(float a, float b) {
  return (unsigned)f2bf(a) | ((unsigned)f2bf(b) << 16);
}

// ---------------------------------------------------------------------------
// Prep: build Bt[tap][n][k] bf16 in workspace.
//   n = opc*4 + q_out  (q minor -> acc regs = quaternion comps)
//   k = c*4   + q_in   (q minor -> one float4 pixel-channel = 8B of k)
// ---------------------------------------------------------------------------
__global__ void prep_bt(const float* __restrict__ wr, const float* __restrict__ wi,
                        const float* __restrict__ wj, const float* __restrict__ wk,
                        unsigned short* __restrict__ btg) {
  int idx = blockIdx.x * 256 + threadIdx.x;          // 9*256*256 = 589824
  if (idx >= 9 * 256 * 256) return;
  int tap = idx >> 16;
  int rem = idx & 65535;
  int n = rem >> 8, k = rem & 255;
  int opc = n >> 2, qo = n & 3, c = k >> 2, qi = k & 3;
  const int   comp[4][4] = {{0,1,2,3},{1,0,3,2},{2,3,0,1},{3,2,1,0}};
  const float sgn [4][4] = {{1.f,-1.f,-1.f,-1.f},{1.f,1.f,-1.f,1.f},
                            {1.f,1.f,1.f,-1.f},{1.f,-1.f,1.f,1.f}};
  int ci = comp[qo][qi];
  const float* wp = (ci == 0) ? wr : (ci == 1) ? wi : (ci == 2) ? wj : wk;
  float v = sgn[qo][qi] * wp[(opc * 64 + c) * 9 + tap];
  btg[idx] = f2bf(v);
}

// ---------------------------------------------------------------------------
// Main: implicit-GEMM quaternion conv, 32x32x16 MFMA.
// R3 structure + R4 conflict-free LDS layout.
// Block: 256 threads = 4 waves; tile = 128 px (2 image rows) x 256 N.
// Wave wn: all 128 px x N quarter [wn*64, wn*64+64). acc[2][4] = 128 AGPR.
// Weights tap-double-buffered in registers from L2-resident btg (wf[2][8]).
// Grid 512 = 2 blocks/CU; each SIMD interleaves 2 independent blocks' waves.
// LDS k-slot-major: xwin[hh 0..3][kslot 0..7][col 0..65] x 16B cells:
//   A-frag read = 512B contiguous, stage write = 1024B contiguous (0 conflicts).
// ---------------------------------------------------------------------------
__launch_bounds__(256, 2)
__global__ void qconv_main(const float* __restrict__ x,
                           const unsigned short* __restrict__ btg,
                           const float* __restrict__ bias,
                           float* __restrict__ out) {
  __shared__ char xwin[4 * 8 * 66 * 16];   // 33792 B

  const int tid = threadIdx.x;
  // XCD-aware swizzle: 512 blocks, 8 XCDs -> 64 consecutive per XCD
  const int nb  = (blockIdx.x & 7) * 64 + (blockIdx.x >> 3);
  const int b   = nb >> 5;              // image
  const int h0  = (nb & 31) * 2;        // first of 2 image rows

  const int lane = tid & 63;
  const int wn   = tid >> 6;            // 0..3: N quarter
  const int l31  = lane & 31;
  const int l32  = lane >> 5;

  const int w_ = lane;                  // staging column 0..63
  const int sh = tid >> 6;              // staging window row 0..3

  // zero-fill padding cols 0 and 65 for all (hh, kslot): 64 x 16B
  if (tid < 64) {
    int hh = tid >> 4, ks = (tid >> 1) & 7, col = (tid & 1) ? 65 : 0;
    *reinterpret_cast<f32x4*>(xwin + ((hh * 8 + ks) * 66 + col) * 16) =
        (f32x4){0.f, 0.f, 0.f, 0.f};
  }

  f32x16 acc[2][4];
#pragma unroll
  for (int i = 0; i < 2; ++i)
#pragma unroll
    for (int j = 0; j < 4; ++j)
      acc[i][j] = (f32x16)(0.f);

  for (int ch = 0; ch < 4; ++ch) {
    __syncthreads();   // previous chunk fully consumed (and pad fill on ch 0)

    // ---- stage: 16 c x 4 rows x 64 cols; channel pair -> one 16B kslot ----
    const int hp = h0 + sh - 1;
    const bool inb = (hp >= 0) && (hp < 64);
#pragma unroll
    for (int i = 0; i < 8; ++i) {        // i == kslot == channel pair
      int c0 = ch * 16 + i * 2;
      float4 v0 = make_float4(0.f, 0.f, 0.f, 0.f), v1 = v0;
      if (inb) {
        const float* p =
            x + (size_t)((((b * 64 + c0) * 64 + hp) * 64 + w_) * 4);
        v0 = *reinterpret_cast<const float4*>(p);
        v1 = *reinterpret_cast<const float4*>(p + 16384);  // next channel
      }
      uint4 u = make_uint4(pk(v0.x, v0.y), pk(v0.z, v0.w),
                           pk(v1.x, v1.y), pk(v1.z, v1.w));
      *reinterpret_cast<uint4*>(
          xwin + ((sh * 8 + i) * 66 + (w_ + 1)) * 16) = u;
    }
    __syncthreads();   // xwin ready

    // per-wave weight base: n = wn*64 + fn*32 + l31, k = ch*64 + kst*16 + l32*8
    const unsigned short* wb =
        btg + (size_t)(wn * 64 + l31) * 256 + ch * 64 + l32 * 8;

    bf16x8 wf[2][8];   // [buf][kst*2+fn], double-buffered across taps
#pragma unroll
    for (int f = 0; f < 8; ++f)
      wf[0][f] = *reinterpret_cast<const bf16x8*>(
          wb + (f & 1) * 8192 + (f >> 1) * 16);

#pragma unroll
    for (int tap = 0; tap < 9; ++tap) {
      const int cur = tap & 1;
      if (tap < 8) {
#pragma unroll
        for (int f = 0; f < 8; ++f)
          wf[cur ^ 1][f] = *reinterpret_cast<const bf16x8*>(
              wb + (tap + 1) * 65536 + (f & 1) * 8192 + (f >> 1) * 16);
      }
      const int dh = tap / 3 - 1;
      const int dw = tap % 3 - 1;
#pragma unroll
      for (int kst = 0; kst < 4; ++kst) {
        bf16x8 pf[4];
#pragma unroll
        for (int fm = 0; fm < 4; ++fm) {
          int pix = fm * 32 + l31;
          int wc  = (pix & 63) + dw + 1;            // 0..65
          int hh  = (pix >> 6) + dh + 1;            // 0..3
          pf[fm] = *reinterpret_cast<const bf16x8*>(
              xwin + ((hh * 8 + kst * 2 + l32) * 66 + wc) * 16);
        }
        __builtin_amdgcn_s_setprio(1);
#pragma unroll
        for (int fn = 0; fn < 2; ++fn)
#pragma unroll
          for (int fm = 0; fm < 4; ++fm)
            acc[fn][fm] = __builtin_amdgcn_mfma_f32_32x32x16_bf16(
                wf[cur][kst * 2 + fn], pf[fm], acc[fn][fm], 0, 0, 0);
        __builtin_amdgcn_s_setprio(0);
      }
    }
  }

  // ---- epilogue: D row=(reg&3)+8*(reg>>2)+4*l32 -> reg&3 == q component ----
#pragma unroll
  for (int fn = 0; fn < 2; ++fn) {
#pragma unroll
    for (int fm = 0; fm < 4; ++fm) {
      int pix = fm * 32 + l31;
      int w   = pix & 63;
      int h   = h0 + (pix >> 6);
#pragma unroll
      for (int g = 0; g < 4; ++g) {
        int opc = wn * 16 + fn * 8 + g * 2 + l32;
        f32x4 v = {acc[fn][fm][4 * g + 0], acc[fn][fm][4 * g + 1],
                   acc[fn][fm][4 * g + 2], acc[fn][fm][4 * g + 3]};
        v.x += bias[opc];   // bias only on real component
        *reinterpret_cast<f32x4*>(
            out + (size_t)((((b * 64 + opc) * 64 + h) * 64 + w) * 4)) = v;
      }
    }
  }
}

extern "C" void kernel_launch(void* const* d_in, const int* in_sizes, int n_in,
                              void* d_out, int out_size, void* d_ws, size_t ws_size,
                              hipStream_t stream) {
  const float* x    = (const float*)d_in[0];
  const float* wr   = (const float*)d_in[1];
  const float* wi   = (const float*)d_in[2];
  const float* wj   = (const float*)d_in[3];
  const float* wk   = (const float*)d_in[4];
  const float* bias = (const float*)d_in[5];
  unsigned short* btg = (unsigned short*)d_ws;   // 9*256*256*2 = 1.18 MB

  prep_bt<<<2304, 256, 0, stream>>>(wr, wi, wj, wk, btg);
  qconv_main<<<512, 256, 0, stream>>>(x, btg, bias, (float*)d_out);
}

// Round 6
// 145.415 us; speedup vs baseline: 1.2978x; 1.0459x over previous
//
#include <hip/hip_runtime.h>

typedef __attribute__((ext_vector_type(8))) short bf16x8;
typedef __attribute__((ext_vector_type(4))) float f32x4;
typedef __attribute__((ext_vector_type(16))) float f32x16;

__device__ __forceinline__ unsigned short f2bf(float f) {
  union { float f; unsigned u; } a; a.f = f;
  unsigned u = a.u;
  u += 0x7fffu + ((u >> 16) & 1u);   // round-to-nearest-even
  return (unsigned short)(u >> 16);
}
__device__ __forceinline__ unsigned pk(float a, float b) {
  return (unsigned)f2bf(a) | ((unsigned)f2bf(b) << 16);
}

// ---------------------------------------------------------------------------
// Prep: build Bt[tap][n][k] bf16 in workspace.
//   n = opc*4 + q_out  (q minor -> acc regs = quaternion comps)
//   k = c*4   + q_in   (q minor -> one float4 pixel-channel = 8B of k)
// ---------------------------------------------------------------------------
__global__ void prep_bt(const float* __restrict__ wr, const float* __restrict__ wi,
                        const float* __restrict__ wj, const float* __restrict__ wk,
                        unsigned short* __restrict__ btg) {
  int idx = blockIdx.x * 256 + threadIdx.x;          // 9*256*256 = 589824
  if (idx >= 9 * 256 * 256) return;
  int tap = idx >> 16;
  int rem = idx & 65535;
  int n = rem >> 8, k = rem & 255;
  int opc = n >> 2, qo = n & 3, c = k >> 2, qi = k & 3;
  const int   comp[4][4] = {{0,1,2,3},{1,0,3,2},{2,3,0,1},{3,2,1,0}};
  const float sgn [4][4] = {{1.f,-1.f,-1.f,-1.f},{1.f,1.f,-1.f,1.f},
                            {1.f,1.f,1.f,-1.f},{1.f,-1.f,1.f,1.f}};
  int ci = comp[qo][qi];
  const float* wp = (ci == 0) ? wr : (ci == 1) ? wi : (ci == 2) ? wj : wk;
  float v = sgn[qo][qi] * wp[(opc * 64 + c) * 9 + tap];
  btg[idx] = f2bf(v);
}

// ---------------------------------------------------------------------------
// Main: implicit-GEMM quaternion conv, 32x32x16 MFMA.
// Block: 256 threads = 4 waves; tile = 128 px (2 image rows) x 256 N.
// Wave wn: all 128 px x N quarter. acc[2][4] = 128 AGPR.
// K pipeline: 8 half-chunks (8 channels = k32 each), LDS DOUBLE-buffered:
//   iter h: compute from buf[h&1] | write h+1 (regs loaded last iter) into
//   buf[(h+1)&1] | issue h+2 global loads | ONE barrier.
//   -> global-load latency hidden under a full compute phase (T14).
// pf (pixel frags) double-buffered pfA/pfB across kst -> ds_read latency
//   hidden under MFMA clusters (counted lgkmcnt).
// Weights tap-double-buffered in regs from L2-resident btg.
// LDS k-slot-major, conflict-free: buf[par][hh 0..3][ks 0..3][col 0..65]x16B.
// ---------------------------------------------------------------------------
__launch_bounds__(256, 2)
__global__ void qconv_main(const float* __restrict__ x,
                           const unsigned short* __restrict__ btg,
                           const float* __restrict__ bias,
                           float* __restrict__ out) {
  __shared__ char xwin[2 * 4 * 4 * 66 * 16];   // 2 x 16896 = 33792 B

  const int tid = threadIdx.x;
  // XCD-aware swizzle: 512 blocks, 8 XCDs -> 64 consecutive per XCD
  const int nb  = (blockIdx.x & 7) * 64 + (blockIdx.x >> 3);
  const int b   = nb >> 5;              // image
  const int h0  = (nb & 31) * 2;        // first of 2 image rows

  const int lane = tid & 63;
  const int wn   = tid >> 6;            // 0..3: N quarter
  const int l31  = lane & 31;
  const int l32  = lane >> 5;

  const int w_ = lane;                  // staging column 0..63
  const int sh = tid >> 6;              // staging window row 0..3
  const int hp = h0 + sh - 1;
  const bool inb = (hp >= 0) && (hp < 64);
  const float* xrow = x + (size_t)(((b * 64) * 64 + hp) * 64 + w_) * 4;

  // zero-fill padding cols 0 and 65 in BOTH buffers (k-independent zeros)
  if (tid < 64) {
    int par = tid >> 5, hh = (tid >> 3) & 3, ks = (tid >> 1) & 3;
    int col = (tid & 1) ? 65 : 0;
    *reinterpret_cast<f32x4*>(
        xwin + par * 16896 + ((hh * 4 + ks) * 66 + col) * 16) =
        (f32x4){0.f, 0.f, 0.f, 0.f};
  }

  f32x16 acc[2][4];
#pragma unroll
  for (int i = 0; i < 2; ++i)
#pragma unroll
    for (int j = 0; j < 4; ++j)
      acc[i][j] = (f32x16)(0.f);

  float4 xr[8];

  // issue the 8 channel loads (one half-chunk) for half H
#define ISSUE(H)                                                               \
  do {                                                                         \
    _Pragma("unroll")                                                          \
    for (int i = 0; i < 8; ++i) {                                              \
      float4 v = make_float4(0.f, 0.f, 0.f, 0.f);                              \
      if (inb)                                                                 \
        v = *reinterpret_cast<const float4*>(xrow + ((H) * 8 + i) * 16384);    \
      xr[i] = v;                                                               \
    }                                                                          \
  } while (0)

  // convert + write xr (half data) into buffer PAR
#define CVTWRITE(PAR)                                                          \
  do {                                                                         \
    char* dst = xwin + (PAR)*16896;                                            \
    _Pragma("unroll")                                                          \
    for (int i = 0; i < 4; ++i) {                                              \
      uint4 u = make_uint4(pk(xr[2 * i].x, xr[2 * i].y),                       \
                           pk(xr[2 * i].z, xr[2 * i].w),                       \
                           pk(xr[2 * i + 1].x, xr[2 * i + 1].y),               \
                           pk(xr[2 * i + 1].z, xr[2 * i + 1].w));              \
      *reinterpret_cast<uint4*>(dst + ((sh * 4 + i) * 66 + (w_ + 1)) * 16) = u;\
    }                                                                          \
  } while (0)

  // prologue: fill buf0 with half 0, issue half 1
  ISSUE(0);
  CVTWRITE(0);
  ISSUE(1);
  __syncthreads();

  for (int h = 0; h < 8; ++h) {
    const char* buf = xwin + (h & 1) * 16896;
    // weight base: n = wn*64 + fn*32 + l31 ; k = h*32 + kst*16 + l32*8
    const unsigned short* wb =
        btg + (size_t)(wn * 64 + l31) * 256 + h * 32 + l32 * 8;

    bf16x8 wf[2][4];   // [buf][kst*2+fn]
#pragma unroll
    for (int f = 0; f < 4; ++f)
      wf[0][f] = *reinterpret_cast<const bf16x8*>(
          wb + (f >> 1) * 16 + (f & 1) * 8192);

    bf16x8 pfA[4], pfB[4];
    // preload pfA: tap 0 (dh=-1, dw=-1), kst=0
#pragma unroll
    for (int fm = 0; fm < 4; ++fm) {
      int hh = (fm >> 1);                       // +dh+1 = +0
      int wc = (fm & 1) * 32 + l31;             // +dw+1 = +0
      pfA[fm] = *reinterpret_cast<const bf16x8*>(
          buf + ((hh * 4 + l32) * 66 + wc) * 16);
    }

#pragma unroll
    for (int tap = 0; tap < 9; ++tap) {
      const int cur = tap & 1;
      const int dh = tap / 3 - 1;
      const int dw = tap % 3 - 1;

      // issue pfB: (tap, kst=1)
#pragma unroll
      for (int fm = 0; fm < 4; ++fm) {
        int hh = (fm >> 1) + dh + 1;
        int wc = (fm & 1) * 32 + l31 + dw + 1;
        pfB[fm] = *reinterpret_cast<const bf16x8*>(
            buf + ((hh * 4 + 2 + l32) * 66 + wc) * 16);
      }
      // prefetch next tap's weights
      if (tap < 8) {
#pragma unroll
        for (int f = 0; f < 4; ++f)
          wf[cur ^ 1][f] = *reinterpret_cast<const bf16x8*>(
              wb + (tap + 1) * 65536 + (f >> 1) * 16 + (f & 1) * 8192);
      }
      // MFMA cluster kst=0 (uses pfA)
#pragma unroll
      for (int fn = 0; fn < 2; ++fn)
#pragma unroll
        for (int fm = 0; fm < 4; ++fm)
          acc[fn][fm] = __builtin_amdgcn_mfma_f32_32x32x16_bf16(
              wf[cur][fn], pfA[fm], acc[fn][fm], 0, 0, 0);

      // issue pfA for (tap+1, kst=0)
      if (tap < 8) {
        const int dh2 = (tap + 1) / 3 - 1;
        const int dw2 = (tap + 1) % 3 - 1;
#pragma unroll
        for (int fm = 0; fm < 4; ++fm) {
          int hh = (fm >> 1) + dh2 + 1;
          int wc = (fm & 1) * 32 + l31 + dw2 + 1;
          pfA[fm] = *reinterpret_cast<const bf16x8*>(
              buf + ((hh * 4 + l32) * 66 + wc) * 16);
        }
      }
      // MFMA cluster kst=1 (uses pfB)
#pragma unroll
      for (int fn = 0; fn < 2; ++fn)
#pragma unroll
        for (int fm = 0; fm < 4; ++fm)
          acc[fn][fm] = __builtin_amdgcn_mfma_f32_32x32x16_bf16(
              wf[cur][2 + fn], pfB[fm], acc[fn][fm], 0, 0, 0);
    }

    // pipeline turn: write half h+1, issue half h+2, one barrier
    if (h < 7) {
      CVTWRITE((h + 1) & 1);
      if (h < 6) ISSUE(h + 2);
    }
    __syncthreads();
  }

  // ---- epilogue: D row=(reg&3)+8*(reg>>2)+4*l32 -> reg&3 == q component ----
#pragma unroll
  for (int fn = 0; fn < 2; ++fn) {
#pragma unroll
    for (int fm = 0; fm < 4; ++fm) {
      int pix = fm * 32 + l31;
      int w   = pix & 63;
      int h   = h0 + (pix >> 6);
#pragma unroll
      for (int g = 0; g < 4; ++g) {
        int opc = wn * 16 + fn * 8 + g * 2 + l32;
        f32x4 v = {acc[fn][fm][4 * g + 0], acc[fn][fm][4 * g + 1],
                   acc[fn][fm][4 * g + 2], acc[fn][fm][4 * g + 3]};
        v.x += bias[opc];   // bias only on real component
        *reinterpret_cast<f32x4*>(
            out + (size_t)((((b * 64 + opc) * 64 + h) * 64 + w) * 4)) = v;
      }
    }
  }
#undef ISSUE
#undef CVTWRITE
}

extern "C" void kernel_launch(void* const* d_in, const int* in_sizes, int n_in,
                              void* d_out, int out_size, void* d_ws, size_t ws_size,
                              hipStream_t stream) {
  const float* x    = (const float*)d_in[0];
  const float* wr   = (const float*)d_in[1];
  const float* wi   = (const float*)d_in[2];
  const float* wj   = (const float*)d_in[3];
  const float* wk   = (const float*)d_in[4];
  const float* bias = (const float*)d_in[5];
  unsigned short* btg = (unsigned short*)d_ws;   // 9*256*256*2 = 1.18 MB

  prep_bt<<<2304, 256, 0, stream>>>(wr, wi, wj, wk, btg);
  qconv_main<<<512, 256, 0, stream>>>(x, btg, bias, (float*)d_out);
}